// Round 2
// baseline (552.289 us; speedup 1.0000x reference)
//
#include <hip/hip_runtime.h>
#include <math.h>

#define NPIX 65536      // 256*256
#define SEG 32          // pixel segments per (b,c)
#define CHUNK 64        // pixels staged per LDS round
#define HEPS (6.4f / 255.0f)

__device__ __forceinline__ float clamp01(float x) { return fminf(fmaxf(x, 0.f), 1.f); }

// grid: 24*SEG blocks, 256 threads. Each block: one (b,c), NPIX/SEG pixels.
// Per lane: 8x8 register tile of the 64x64 histogram (outer-product GEMM style).
__global__ __launch_bounds__(256) void hist_kernel(const float* __restrict__ rgbd,
                                                   float* __restrict__ H) {
  const int blk = blockIdx.x;
  const int seg = blk % SEG;
  const int bc  = blk / SEG;   // 0..23
  const int b = bc / 3;
  const int c = bc - 3 * b;
  const int t = threadIdx.x;
  const int lane = t & 63;
  const int wave = t >> 6;

  // stride 68 (=4 mod 32 words): eval-phase b128 stores conflict-free,
  // FMA-phase b128 reads 2-way (free per m136-class behavior).
  __shared__ float sU[CHUNK][68];  // a = Iy * ku
  __shared__ float sV[CHUNK][68];  // kv

  const float* __restrict__ base = rgbd + (size_t)b * (4 * NPIX);

  float acc[8][8];
#pragma unroll
  for (int i = 0; i < 8; ++i)
#pragma unroll
    for (int j = 0; j < 8; ++j) acc[i][j] = 0.f;

  const int u0 = (lane & 7) * 8;   // this lane's u-tile
  const int v0 = (lane >> 3) * 8;  // this lane's v-tile
  const int ep = t >> 2;           // eval pixel 0..63
  const int eq = t & 3;            // eval quarter (16 bins each)

  const int p0 = seg * (NPIX / SEG);

  for (int ch = 0; ch < (NPIX / SEG) / CHUNK; ++ch) {
    // ---- eval phase: 4 threads per pixel, each computes 16 (a,kv) pairs ----
    const int pix = p0 + ch * CHUNK + ep;
    float r  = clamp01(0.5f * (base[pix] + 1.f));
    float g  = clamp01(0.5f * (base[NPIX + pix] + 1.f));
    float bl = clamp01(0.5f * (base[2 * NPIX + pix] + 1.f));
    float Iy = sqrtf(r * r + g * g + bl * bl + HEPS);
    float lr = __logf(r + HEPS);
    float lg = __logf(g + HEPS);
    float lb = __logf(bl + HEPS);
    float u, v;
    if (c == 0)      { u = lr - lg; v = lr - lb; }
    else if (c == 1) { u = lg - lr; v = lg - lb; }
    else             { u = lb - lr; v = lb - lg; }

#pragma unroll
    for (int jj = 0; jj < 4; ++jj) {
      float4 au, kv;
      float* pa = (float*)&au;
      float* pv = (float*)&kv;
#pragma unroll
      for (int e = 0; e < 4; ++e) {
        const int k = eq * 16 + jj * 4 + e;
        const float dlt = -3.f + (float)k * (6.f / 63.f);
        const float du = u - dlt;
        const float dv = v - dlt;
        pa[e] = Iy * __builtin_amdgcn_rcpf(fmaf(du * du, 2500.f, 1.f));
        pv[e] = __builtin_amdgcn_rcpf(fmaf(dv * dv, 2500.f, 1.f));
      }
      *(float4*)&sU[ep][eq * 16 + jj * 4] = au;
      *(float4*)&sV[ep][eq * 16 + jj * 4] = kv;
    }
    __syncthreads();

    // ---- FMA phase: each wave consumes 16 pixels, rank-1 updates its tiles ----
#pragma unroll 1
    for (int pp = 0; pp < 16; ++pp) {
      const int p = (wave << 4) + pp;
      float a[8], bb[8];
      *(float4*)&a[0]  = *(const float4*)&sU[p][u0];
      *(float4*)&a[4]  = *(const float4*)&sU[p][u0 + 4];
      *(float4*)&bb[0] = *(const float4*)&sV[p][v0];
      *(float4*)&bb[4] = *(const float4*)&sV[p][v0 + 4];
#pragma unroll
      for (int i = 0; i < 8; ++i)
#pragma unroll
        for (int j = 0; j < 8; ++j)
          acc[i][j] = fmaf(a[i], bb[j], acc[i][j]);
    }
    __syncthreads();
  }

  float* __restrict__ Hbc = H + bc * 4096;
#pragma unroll
  for (int i = 0; i < 8; ++i)
#pragma unroll
    for (int j = 0; j < 8; ++j)
      atomicAdd(&Hbc[(u0 + i) * 64 + (v0 + j)], acc[i][j]);
}

// one block per batch element: norm[b] = sum over 3*64*64 + EPS
__global__ __launch_bounds__(256) void norm_kernel(const float* __restrict__ H,
                                                   float* __restrict__ norms) {
  const int b = blockIdx.x;
  const float* __restrict__ Hb = H + b * 12288;
  float s = 0.f;
  for (int i = threadIdx.x; i < 12288; i += 256) s += Hb[i];
  __shared__ float red[4];
#pragma unroll
  for (int off = 32; off > 0; off >>= 1) s += __shfl_down(s, off);
  if ((threadIdx.x & 63) == 0) red[threadIdx.x >> 6] = s;
  __syncthreads();
  if (threadIdx.x == 0) norms[b] = red[0] + red[1] + red[2] + red[3] + HEPS;
}

// sum of (sqrt(th) - sqrt(h/norm))^2 over [8,3,64,64] -> atomicAdd into acc
__global__ __launch_bounds__(256) void loss_kernel(const float* __restrict__ H,
                                                   const float* __restrict__ norms,
                                                   const float* __restrict__ th,
                                                   float* __restrict__ acc) {
  float s = 0.f;
  for (int idx = blockIdx.x * 256 + threadIdx.x; idx < 8 * 12288;
       idx += gridDim.x * 256) {
    const int b = idx / 12288;
    const int r = idx - b * 12288;
    const float h = H[idx] / norms[b];
    const float d = sqrtf(th[r]) - sqrtf(h);
    s += d * d;
  }
  __shared__ float red[4];
#pragma unroll
  for (int off = 32; off > 0; off >>= 1) s += __shfl_down(s, off);
  if ((threadIdx.x & 63) == 0) red[threadIdx.x >> 6] = s;
  __syncthreads();
  if (threadIdx.x == 0) atomicAdd(acc, red[0] + red[1] + red[2] + red[3]);
}

__global__ void final_kernel(const float* __restrict__ acc, float* __restrict__ out) {
  // (1/sqrt(2)) * sqrt(sum) / B,  B = 8
  out[0] = sqrtf(acc[0]) * 0.08838834764831845f;
}

extern "C" void kernel_launch(void* const* d_in, const int* in_sizes, int n_in,
                              void* d_out, int out_size, void* d_ws, size_t ws_size,
                              hipStream_t stream) {
  const float* rgbd = (const float*)d_in[0];   // [8,4,256,256]
  const float* th   = (const float*)d_in[1];   // [3,64,64]
  float* out = (float*)d_out;

  float* H     = (float*)d_ws;        // [24][4096]
  float* norms = H + 24 * 4096;       // [8]
  float* acc   = norms + 8;           // [1]

  hipMemsetAsync(d_ws, 0, (size_t)(24 * 4096 + 16) * sizeof(float), stream);
  hist_kernel<<<24 * SEG, 256, 0, stream>>>(rgbd, H);
  norm_kernel<<<8, 256, 0, stream>>>(H, norms);
  loss_kernel<<<96, 256, 0, stream>>>(H, norms, th, acc);
  final_kernel<<<1, 1, 0, stream>>>(acc, out);
}

// Round 3
// 198.180 us; speedup vs baseline: 2.7868x; 2.7868x over previous
//
#include <hip/hip_runtime.h>
#include <hip/hip_bf16.h>
#include <math.h>

#define NPIX 65536      // 256*256
#define SEGB 32         // segments per (b,c)
#define HEPS (6.4f / 255.0f)

typedef __bf16 bf16x8 __attribute__((ext_vector_type(8)));
typedef float  f32x4  __attribute__((ext_vector_type(4)));

__device__ __forceinline__ float clamp01(float x) { return fminf(fmaxf(x, 0.f), 1.f); }

// grid: 24*SEGB blocks, 512 threads (8 waves). Each wave computes the full
// 64x64 histogram for its pixel slice via 4x4 tiles of mfma_f32_16x16x32_bf16,
// evaluating A/B fragments directly in registers (no big LDS staging).
// PART=1: write per-block partial hist (no atomics). PART=0: atomicAdd into H.
template <int PART>
__global__ __launch_bounds__(512) void hist_mfma(const float* __restrict__ rgbd,
                                                 float* __restrict__ out) {
  const int blk = blockIdx.x;
  const int seg = blk & (SEGB - 1);
  const int bc  = blk / SEGB;     // 0..23
  const int b = bc / 3;
  const int c = bc - 3 * b;
  const int t = threadIdx.x;
  const int l = t & 63;
  const int w = t >> 6;           // wave 0..7

  __shared__ float stage[8][3][64];   // per-wave u/v/iy staging (wave-private)
  __shared__ float red[4096];         // block-level 64x64 reduction

  const float* __restrict__ base = rgbd + (size_t)b * (4 * NPIX);

  f32x4 acc[4][4];
#pragma unroll
  for (int i = 0; i < 4; ++i)
#pragma unroll
    for (int j = 0; j < 4; ++j) acc[i][j] = (f32x4){0.f, 0.f, 0.f, 0.f};

  const int halfq = l & 15;   // A: output row m (u-bin low 4 bits); B: output col n (v-bin)
  const int grp   = l >> 4;   // k-group: this lane holds k = 8*grp + j
  const float d0  = -3.f + (float)halfq * (6.f / 63.f);
  const float dstep = 16.f * 6.f / 63.f;   // delta offset between 16-bin tiles

  // this wave's pixels: 256, processed 64/iter
  const int p0  = seg * (NPIX / SEGB) + w * (NPIX / SEGB / 8);
  const int NIT = (NPIX / SEGB / 8) / 64;  // 4

  // prefetch iter 0 (lane l -> pixel p0+l)
  float pr = base[p0 + l];
  float pg = base[NPIX + p0 + l];
  float pb = base[2 * NPIX + p0 + l];

  for (int it = 0; it < NIT; ++it) {
    // ---- per-pixel scalars ----
    float r  = clamp01(0.5f * (pr + 1.f));
    float g  = clamp01(0.5f * (pg + 1.f));
    float bl = clamp01(0.5f * (pb + 1.f));
    float iy = sqrtf(fmaf(r, r, fmaf(g, g, fmaf(bl, bl, HEPS))));
    float lr = __logf(r + HEPS);
    float lg = __logf(g + HEPS);
    float lb = __logf(bl + HEPS);
    float u, v;
    if (c == 0)      { u = lr - lg; v = lr - lb; }
    else if (c == 1) { u = lg - lr; v = lg - lb; }
    else             { u = lb - lr; v = lb - lg; }
    stage[w][0][l] = u;
    stage[w][1][l] = v;
    stage[w][2][l] = iy;

    // prefetch next iteration's pixels (hide vmem latency under eval)
    if (it + 1 < NIT) {
      const int p = p0 + (it + 1) * 64 + l;
      pr = base[p]; pg = base[NPIX + p]; pb = base[2 * NPIX + p];
    }
    // wave-private LDS: in-order per wave; waitcnt orders write->read
    asm volatile("s_waitcnt lgkmcnt(0)" ::: "memory");

    // ---- two K-subtiles of 32 pixels each ----
#pragma unroll
    for (int s = 0; s < 2; ++s) {
      const int k0 = s * 32 + grp * 8;   // this lane's 8 pixels (contiguous)
      float u8[8], iy8[8], v8[8];
      *(f32x4*)&u8[0]  = *(const f32x4*)&stage[w][0][k0];
      *(f32x4*)&u8[4]  = *(const f32x4*)&stage[w][0][k0 + 4];
      *(f32x4*)&iy8[0] = *(const f32x4*)&stage[w][2][k0];
      *(f32x4*)&iy8[4] = *(const f32x4*)&stage[w][2][k0 + 4];

      bf16x8 af[4];
#pragma unroll
      for (int ut = 0; ut < 4; ++ut) {
        const float dlt = d0 + (float)ut * dstep;
#pragma unroll
        for (int j = 0; j < 8; ++j) {
          const float du = u8[j] - dlt;
          const float x  = du * 50.f;              // 1/sigma = 50
          const float q  = fmaf(x, x, 1.f);
          af[ut][j] = (__bf16)(iy8[j] * __builtin_amdgcn_rcpf(q));
        }
      }

      *(f32x4*)&v8[0] = *(const f32x4*)&stage[w][1][k0];
      *(f32x4*)&v8[4] = *(const f32x4*)&stage[w][1][k0 + 4];

#pragma unroll
      for (int vt = 0; vt < 4; ++vt) {
        const float dlt = d0 + (float)vt * dstep;
        bf16x8 bf;
#pragma unroll
        for (int j = 0; j < 8; ++j) {
          const float dv = v8[j] - dlt;
          const float x  = dv * 50.f;
          const float q  = fmaf(x, x, 1.f);
          bf[j] = (__bf16)__builtin_amdgcn_rcpf(q);
        }
#pragma unroll
        for (int ut = 0; ut < 4; ++ut)
          acc[ut][vt] = __builtin_amdgcn_mfma_f32_16x16x32_bf16(af[ut], bf, acc[ut][vt], 0, 0, 0);
      }
    }
  }

  // ---- block reduction: wave-serial add into red (C/D layout: col=lane&15,
  // row=(lane>>4)*4+reg  [HW-verified m89/m91]) ----
  for (int ww = 0; ww < 8; ++ww) {
    if (w == ww) {
#pragma unroll
      for (int ut = 0; ut < 4; ++ut)
#pragma unroll
        for (int vt = 0; vt < 4; ++vt)
#pragma unroll
          for (int rg = 0; rg < 4; ++rg) {
            const int row = ut * 16 + grp * 4 + rg;
            const int col = vt * 16 + halfq;
            if (ww == 0) red[row * 64 + col]  = acc[ut][vt][rg];
            else         red[row * 64 + col] += acc[ut][vt][rg];
          }
    }
    __syncthreads();
  }

  if (PART) {
    float* __restrict__ P = out + (size_t)blk * 4096;
    for (int i = t; i < 4096; i += 512) P[i] = red[i];
  } else {
    float* __restrict__ Hbc = out + (size_t)bc * 4096;
    for (int i = t; i < 4096; i += 512) atomicAdd(&Hbc[i], red[i]);
  }
}

// ---- partials path: per-b reduce + norm + Hellinger partial, fused ----
__global__ __launch_bounds__(256) void reduce_loss(const float* __restrict__ P,
                                                   const float* __restrict__ th,
                                                   float* __restrict__ acc) {
  const int b = blockIdx.x;
  const int t = threadIdx.x;
  __shared__ float hb[12288];
  __shared__ float rbuf[4];

  float npart = 0.f;
  for (int e = t; e < 12288; e += 256) {
    const int c = e >> 12, bin = e & 4095;
    const float* __restrict__ p0 = P + (size_t)((b * 3 + c) * SEGB) * 4096 + bin;
    float s = 0.f;
#pragma unroll
    for (int sg = 0; sg < SEGB; ++sg) s += p0[(size_t)sg * 4096];
    hb[e] = s;
    npart += s;
  }
#pragma unroll
  for (int off = 32; off > 0; off >>= 1) npart += __shfl_down(npart, off);
  if ((t & 63) == 0) rbuf[t >> 6] = npart;
  __syncthreads();
  const float norm = rbuf[0] + rbuf[1] + rbuf[2] + rbuf[3] + HEPS;
  const float invn = 1.f / norm;

  float ls = 0.f;
  for (int e = t; e < 12288; e += 256) {
    const float d = sqrtf(th[e]) - sqrtf(hb[e] * invn);
    ls += d * d;
  }
#pragma unroll
  for (int off = 32; off > 0; off >>= 1) ls += __shfl_down(ls, off);
  __syncthreads();
  if ((t & 63) == 0) rbuf[t >> 6] = ls;
  __syncthreads();
  if (t == 0) atomicAdd(acc, rbuf[0] + rbuf[1] + rbuf[2] + rbuf[3]);
}

// ---- fallback (atomic) path helpers, as in round 2 ----
__global__ __launch_bounds__(256) void norm_kernel(const float* __restrict__ H,
                                                   float* __restrict__ norms) {
  const int b = blockIdx.x;
  const float* __restrict__ Hb = H + b * 12288;
  float s = 0.f;
  for (int i = threadIdx.x; i < 12288; i += 256) s += Hb[i];
  __shared__ float red[4];
#pragma unroll
  for (int off = 32; off > 0; off >>= 1) s += __shfl_down(s, off);
  if ((threadIdx.x & 63) == 0) red[threadIdx.x >> 6] = s;
  __syncthreads();
  if (threadIdx.x == 0) norms[b] = red[0] + red[1] + red[2] + red[3] + HEPS;
}

__global__ __launch_bounds__(256) void loss_kernel(const float* __restrict__ H,
                                                   const float* __restrict__ norms,
                                                   const float* __restrict__ th,
                                                   float* __restrict__ acc) {
  float s = 0.f;
  for (int idx = blockIdx.x * 256 + threadIdx.x; idx < 8 * 12288;
       idx += gridDim.x * 256) {
    const int b = idx / 12288;
    const int r = idx - b * 12288;
    const float h = H[idx] / norms[b];
    const float d = sqrtf(th[r]) - sqrtf(h);
    s += d * d;
  }
  __shared__ float red[4];
#pragma unroll
  for (int off = 32; off > 0; off >>= 1) s += __shfl_down(s, off);
  if ((threadIdx.x & 63) == 0) red[threadIdx.x >> 6] = s;
  __syncthreads();
  if (threadIdx.x == 0) atomicAdd(acc, red[0] + red[1] + red[2] + red[3]);
}

__global__ void final_kernel(const float* __restrict__ acc, float* __restrict__ out) {
  // (1/sqrt(2)) * sqrt(sum) / B,  B = 8
  out[0] = sqrtf(acc[0]) * 0.08838834764831845f;
}

extern "C" void kernel_launch(void* const* d_in, const int* in_sizes, int n_in,
                              void* d_out, int out_size, void* d_ws, size_t ws_size,
                              hipStream_t stream) {
  const float* rgbd = (const float*)d_in[0];   // [8,4,256,256]
  const float* th   = (const float*)d_in[1];   // [3,64,64]
  float* out = (float*)d_out;

  const size_t nP = (size_t)24 * SEGB * 4096;          // partial hists
  if (ws_size >= (nP + 64) * sizeof(float)) {
    // ---- no-atomic path: per-block partials + fused reduce/loss ----
    float* P   = (float*)d_ws;
    float* acc = P + nP;
    hipMemsetAsync(acc, 0, sizeof(float), stream);
    hist_mfma<1><<<24 * SEGB, 512, 0, stream>>>(rgbd, P);
    reduce_loss<<<8, 256, 0, stream>>>(P, th, acc);
    final_kernel<<<1, 1, 0, stream>>>(acc, out);
  } else {
    // ---- fallback: atomics into H (4096 per block) ----
    float* H     = (float*)d_ws;      // [24][4096]
    float* norms = H + 24 * 4096;     // [8]
    float* acc   = norms + 8;         // [1]
    hipMemsetAsync(d_ws, 0, (size_t)(24 * 4096 + 16) * sizeof(float), stream);
    hist_mfma<0><<<24 * SEGB, 512, 0, stream>>>(rgbd, H);
    norm_kernel<<<8, 256, 0, stream>>>(H, norms);
    loss_kernel<<<96, 256, 0, stream>>>(H, norms, th, acc);
    final_kernel<<<1, 1, 0, stream>>>(acc, out);
  }
}

// Round 4
// 129.018 us; speedup vs baseline: 4.2807x; 1.5361x over previous
//
#include <hip/hip_runtime.h>
#include <hip/hip_bf16.h>
#include <math.h>

#define NPIX 65536      // 256*256
#define SEGB 32         // segments per (b,c)
#define HEPS (6.4f / 255.0f)

typedef __bf16 bf16x8 __attribute__((ext_vector_type(8)));
typedef float  f32x4  __attribute__((ext_vector_type(4)));

__device__ __forceinline__ float clamp01(float x) { return fminf(fmaxf(x, 0.f), 1.f); }

// grid: 24*SEGB blocks, 512 threads (8 waves). Each wave computes the full
// 64x64 histogram for its pixel slice via 4x4 tiles of mfma_f32_16x16x32_bf16,
// evaluating A/B fragments directly in registers (no big LDS staging).
// PART=1: write per-block partial hist (no atomics). PART=0: atomicAdd into H.
template <int PART>
__global__ __launch_bounds__(512) void hist_mfma(const float* __restrict__ rgbd,
                                                 float* __restrict__ out) {
  const int blk = blockIdx.x;
  const int seg = blk & (SEGB - 1);
  const int bc  = blk / SEGB;     // 0..23
  const int b = bc / 3;
  const int c = bc - 3 * b;
  const int t = threadIdx.x;
  const int l = t & 63;
  const int w = t >> 6;           // wave 0..7

  __shared__ float stage[8][3][64];   // per-wave u/v/iy staging (wave-private)
  __shared__ float red[4096];         // block-level 64x64 reduction

  const float* __restrict__ base = rgbd + (size_t)b * (4 * NPIX);

  f32x4 acc[4][4];
#pragma unroll
  for (int i = 0; i < 4; ++i)
#pragma unroll
    for (int j = 0; j < 4; ++j) acc[i][j] = (f32x4){0.f, 0.f, 0.f, 0.f};

  const int halfq = l & 15;   // A: output row m (u-bin low 4 bits); B: output col n (v-bin)
  const int grp   = l >> 4;   // k-group: this lane holds k = 8*grp + j
  const float d0  = -3.f + (float)halfq * (6.f / 63.f);
  const float dstep = 16.f * 6.f / 63.f;   // delta offset between 16-bin tiles

  // this wave's pixels: 256, processed 64/iter
  const int p0  = seg * (NPIX / SEGB) + w * (NPIX / SEGB / 8);
  const int NIT = (NPIX / SEGB / 8) / 64;  // 4

  // prefetch iter 0 (lane l -> pixel p0+l)
  float pr = base[p0 + l];
  float pg = base[NPIX + p0 + l];
  float pb = base[2 * NPIX + p0 + l];

  for (int it = 0; it < NIT; ++it) {
    // ---- per-pixel scalars ----
    float r  = clamp01(0.5f * (pr + 1.f));
    float g  = clamp01(0.5f * (pg + 1.f));
    float bl = clamp01(0.5f * (pb + 1.f));
    float iy = sqrtf(fmaf(r, r, fmaf(g, g, fmaf(bl, bl, HEPS))));
    float lr = __logf(r + HEPS);
    float lg = __logf(g + HEPS);
    float lb = __logf(bl + HEPS);
    float u, v;
    if (c == 0)      { u = lr - lg; v = lr - lb; }
    else if (c == 1) { u = lg - lr; v = lg - lb; }
    else             { u = lb - lr; v = lb - lg; }
    stage[w][0][l] = u;
    stage[w][1][l] = v;
    stage[w][2][l] = iy;

    // prefetch next iteration's pixels (hide vmem latency under eval)
    if (it + 1 < NIT) {
      const int p = p0 + (it + 1) * 64 + l;
      pr = base[p]; pg = base[NPIX + p]; pb = base[2 * NPIX + p];
    }
    // wave-private LDS: in-order per wave; waitcnt orders write->read
    asm volatile("s_waitcnt lgkmcnt(0)" ::: "memory");

    // ---- two K-subtiles of 32 pixels each ----
#pragma unroll
    for (int s = 0; s < 2; ++s) {
      const int k0 = s * 32 + grp * 8;   // this lane's 8 pixels (contiguous)
      float u8[8], iy8[8], v8[8];
      *(f32x4*)&u8[0]  = *(const f32x4*)&stage[w][0][k0];
      *(f32x4*)&u8[4]  = *(const f32x4*)&stage[w][0][k0 + 4];
      *(f32x4*)&iy8[0] = *(const f32x4*)&stage[w][2][k0];
      *(f32x4*)&iy8[4] = *(const f32x4*)&stage[w][2][k0 + 4];

      bf16x8 af[4];
#pragma unroll
      for (int ut = 0; ut < 4; ++ut) {
        const float dlt = d0 + (float)ut * dstep;
#pragma unroll
        for (int j = 0; j < 8; ++j) {
          const float du = u8[j] - dlt;
          const float x  = du * 50.f;              // 1/sigma = 50
          const float q  = fmaf(x, x, 1.f);
          af[ut][j] = (__bf16)(iy8[j] * __builtin_amdgcn_rcpf(q));
        }
      }

      *(f32x4*)&v8[0] = *(const f32x4*)&stage[w][1][k0];
      *(f32x4*)&v8[4] = *(const f32x4*)&stage[w][1][k0 + 4];

#pragma unroll
      for (int vt = 0; vt < 4; ++vt) {
        const float dlt = d0 + (float)vt * dstep;
        bf16x8 bf;
#pragma unroll
        for (int j = 0; j < 8; ++j) {
          const float dv = v8[j] - dlt;
          const float x  = dv * 50.f;
          const float q  = fmaf(x, x, 1.f);
          bf[j] = (__bf16)__builtin_amdgcn_rcpf(q);
        }
#pragma unroll
        for (int ut = 0; ut < 4; ++ut)
          acc[ut][vt] = __builtin_amdgcn_mfma_f32_16x16x32_bf16(af[ut], bf, acc[ut][vt], 0, 0, 0);
      }
    }
  }

  // ---- block reduction: wave-serial add into red (C/D layout: col=lane&15,
  // row=(lane>>4)*4+reg  [HW-verified m89/m91]) ----
  for (int ww = 0; ww < 8; ++ww) {
    if (w == ww) {
#pragma unroll
      for (int ut = 0; ut < 4; ++ut)
#pragma unroll
        for (int vt = 0; vt < 4; ++vt)
#pragma unroll
          for (int rg = 0; rg < 4; ++rg) {
            const int row = ut * 16 + grp * 4 + rg;
            const int col = vt * 16 + halfq;
            if (ww == 0) red[row * 64 + col]  = acc[ut][vt][rg];
            else         red[row * 64 + col] += acc[ut][vt][rg];
          }
    }
    __syncthreads();
  }

  if (PART) {
    float* __restrict__ P = out + (size_t)blk * 4096;
    for (int i = t; i < 4096; i += 512) P[i] = red[i];
  } else {
    float* __restrict__ Hbc = out + (size_t)bc * 4096;
    for (int i = t; i < 4096; i += 512) atomicAdd(&Hbc[i], red[i]);
  }
}

// ---- stage 2: parallel partial reduction ----
// grid 384 x 256: thread e = (bc, bin). Sums SEGB partials, writes the result
// IN-PLACE into segment-0 slice of P, and atomically accumulates per-b norm.
__global__ __launch_bounds__(256) void reduce_partials(float* __restrict__ P,
                                                       float* __restrict__ norms) {
  const int e   = blockIdx.x * 256 + threadIdx.x;   // 0..98303
  const int bc  = e >> 12;
  const int bin = e & 4095;
  float* __restrict__ p0 = P + (size_t)(bc * SEGB) * 4096 + bin;
  float s = 0.f;
#pragma unroll
  for (int sg = 0; sg < SEGB; ++sg) s += p0[(size_t)sg * 4096];
  p0[0] = s;  // in-place: segment-0 slice now holds the reduced hist

  // per-block (single-b) norm contribution
  __shared__ float red[4];
  float ns = s;
#pragma unroll
  for (int off = 32; off > 0; off >>= 1) ns += __shfl_down(ns, off);
  if ((threadIdx.x & 63) == 0) red[threadIdx.x >> 6] = ns;
  __syncthreads();
  if (threadIdx.x == 0)
    atomicAdd(&norms[bc / 3], red[0] + red[1] + red[2] + red[3]);
}

// ---- stage 3: Hellinger loss over the reduced hists (seg-0 slices of P) ----
__global__ __launch_bounds__(256) void loss_partials(const float* __restrict__ P,
                                                     const float* __restrict__ norms,
                                                     const float* __restrict__ th,
                                                     float* __restrict__ acc) {
  float s = 0.f;
  for (int idx = blockIdx.x * 256 + threadIdx.x; idx < 8 * 12288;
       idx += gridDim.x * 256) {
    const int b   = idx / 12288;
    const int r   = idx - b * 12288;
    const int c   = r >> 12;
    const int bin = r & 4095;
    const float h = P[(size_t)((b * 3 + c) * SEGB) * 4096 + bin] / (norms[b] + HEPS);
    const float d = sqrtf(th[r]) - sqrtf(h);
    s += d * d;
  }
  __shared__ float red[4];
#pragma unroll
  for (int off = 32; off > 0; off >>= 1) s += __shfl_down(s, off);
  if ((threadIdx.x & 63) == 0) red[threadIdx.x >> 6] = s;
  __syncthreads();
  if (threadIdx.x == 0) atomicAdd(acc, red[0] + red[1] + red[2] + red[3]);
}

// ---- fallback (atomic) path helpers ----
__global__ __launch_bounds__(256) void norm_kernel(const float* __restrict__ H,
                                                   float* __restrict__ norms) {
  const int b = blockIdx.x;
  const float* __restrict__ Hb = H + b * 12288;
  float s = 0.f;
  for (int i = threadIdx.x; i < 12288; i += 256) s += Hb[i];
  __shared__ float red[4];
#pragma unroll
  for (int off = 32; off > 0; off >>= 1) s += __shfl_down(s, off);
  if ((threadIdx.x & 63) == 0) red[threadIdx.x >> 6] = s;
  __syncthreads();
  if (threadIdx.x == 0) norms[b] = red[0] + red[1] + red[2] + red[3] + HEPS;
}

__global__ __launch_bounds__(256) void loss_kernel(const float* __restrict__ H,
                                                   const float* __restrict__ norms,
                                                   const float* __restrict__ th,
                                                   float* __restrict__ acc) {
  float s = 0.f;
  for (int idx = blockIdx.x * 256 + threadIdx.x; idx < 8 * 12288;
       idx += gridDim.x * 256) {
    const int b = idx / 12288;
    const int r = idx - b * 12288;
    const float h = H[idx] / norms[b];
    const float d = sqrtf(th[r]) - sqrtf(h);
    s += d * d;
  }
  __shared__ float red[4];
#pragma unroll
  for (int off = 32; off > 0; off >>= 1) s += __shfl_down(s, off);
  if ((threadIdx.x & 63) == 0) red[threadIdx.x >> 6] = s;
  __syncthreads();
  if (threadIdx.x == 0) atomicAdd(acc, red[0] + red[1] + red[2] + red[3]);
}

__global__ void final_kernel(const float* __restrict__ acc, float* __restrict__ out) {
  // (1/sqrt(2)) * sqrt(sum) / B,  B = 8
  out[0] = sqrtf(acc[0]) * 0.08838834764831845f;
}

extern "C" void kernel_launch(void* const* d_in, const int* in_sizes, int n_in,
                              void* d_out, int out_size, void* d_ws, size_t ws_size,
                              hipStream_t stream) {
  const float* rgbd = (const float*)d_in[0];   // [8,4,256,256]
  const float* th   = (const float*)d_in[1];   // [3,64,64]
  float* out = (float*)d_out;

  const size_t nP = (size_t)24 * SEGB * 4096;          // partial hists
  if (ws_size >= (nP + 64) * sizeof(float)) {
    // ---- no-atomic path: per-block partials + parallel reduce + loss ----
    float* P     = (float*)d_ws;
    float* norms = P + nP;          // [8]
    float* acc   = norms + 8;       // [1]
    hipMemsetAsync(norms, 0, 16 * sizeof(float), stream);
    hist_mfma<1><<<24 * SEGB, 512, 0, stream>>>(rgbd, P);
    reduce_partials<<<384, 256, 0, stream>>>(P, norms);
    loss_partials<<<96, 256, 0, stream>>>(P, norms, th, acc);
    final_kernel<<<1, 1, 0, stream>>>(acc, out);
  } else {
    // ---- fallback: atomics into H (4096 per block) ----
    float* H     = (float*)d_ws;      // [24][4096]
    float* norms = H + 24 * 4096;     // [8]
    float* acc   = norms + 8;         // [1]
    hipMemsetAsync(d_ws, 0, (size_t)(24 * 4096 + 16) * sizeof(float), stream);
    hist_mfma<0><<<24 * SEGB, 512, 0, stream>>>(rgbd, H);
    norm_kernel<<<8, 256, 0, stream>>>(H, norms);
    loss_kernel<<<96, 256, 0, stream>>>(H, norms, th, acc);
    final_kernel<<<1, 1, 0, stream>>>(acc, out);
  }
}

// Round 5
// 108.655 us; speedup vs baseline: 5.0830x; 1.1874x over previous
//
#include <hip/hip_runtime.h>
#include <hip/hip_bf16.h>
#include <math.h>

#define NPIX 65536      // 256*256
#define SEGB 32         // segments per (b,c)
#define HEPS (6.4f / 255.0f)

typedef __bf16 bf16x8 __attribute__((ext_vector_type(8)));
typedef float  f32x4  __attribute__((ext_vector_type(4)));
typedef float  f32x2  __attribute__((ext_vector_type(2)));

__device__ __forceinline__ float clamp01(float x) { return fminf(fmaxf(x, 0.f), 1.f); }

// grid: 24*SEGB blocks, 256 threads (4 waves). Each wave computes the full
// 64x64 histogram for its 512 pixels via 4x4 tiles of mfma_f32_16x16x32_bf16.
// Epilogue: vectorized LDS tree reduction (no scalar RMW, 3 barriers), then
// wave 0 stores the block partial in FRAGMENT-PERMUTED layout (coalesced
// dwordx4); the loss kernel un-permutes when indexing th.
// Block 0 also zero-inits the 16-float control region (norms/acc/counter).
__global__ __launch_bounds__(256) void hist_mfma(const float* __restrict__ rgbd,
                                                 float* __restrict__ P,
                                                 float* __restrict__ ctrl) {
  const int blk = blockIdx.x;
  const int seg = blk & (SEGB - 1);
  const int bc  = blk / SEGB;     // 0..23
  const int b = bc / 3;
  const int c = bc - 3 * b;
  const int t = threadIdx.x;
  const int l = t & 63;
  const int w = t >> 6;           // wave 0..3

  if (blk == 0 && t < 16) ctrl[t] = 0.f;   // norms[8], acc, counter, pad

  __shared__ float stage[4][3][64];   // per-wave u50/v50/iy staging
  __shared__ f32x4 slab[2][16][64];   // reduction slabs (fragment layout)

  const float* __restrict__ base = rgbd + (size_t)b * (4 * NPIX);

  f32x4 acc[16];
#pragma unroll
  for (int i = 0; i < 16; ++i) acc[i] = (f32x4){0.f, 0.f, 0.f, 0.f};

  const int halfq = l & 15;   // output col within 16-tile
  const int grp   = l >> 4;   // k-group / output row group
  const float d50_0   = (-3.f + (float)halfq * (6.f / 63.f)) * 50.f;  // delta/sigma
  const float dstep50 = (16.f * 6.f / 63.f) * 50.f;
  const f32x2 one2 = {1.f, 1.f};

  // this wave's pixels: 512, processed 64/iter
  const int p0 = seg * 2048 + w * 512;

  float pr = base[p0 + l];
  float pg = base[NPIX + p0 + l];
  float pb = base[2 * NPIX + p0 + l];

  for (int it = 0; it < 8; ++it) {
    // ---- per-pixel scalars ----
    float r  = clamp01(fmaf(pr, 0.5f, 0.5f));
    float g  = clamp01(fmaf(pg, 0.5f, 0.5f));
    float bl = clamp01(fmaf(pb, 0.5f, 0.5f));
    float iy = sqrtf(fmaf(r, r, fmaf(g, g, fmaf(bl, bl, HEPS))));
    float lr = __logf(r + HEPS);
    float lg = __logf(g + HEPS);
    float lb = __logf(bl + HEPS);
    float u, v;
    if (c == 0)      { u = lr - lg; v = lr - lb; }
    else if (c == 1) { u = lg - lr; v = lg - lb; }
    else             { u = lb - lr; v = lb - lg; }
    stage[w][0][l] = u * 50.f;     // u/sigma
    stage[w][1][l] = v * 50.f;
    stage[w][2][l] = iy;

    if (it + 1 < 8) {  // prefetch next 64 pixels
      const int p = p0 + (it + 1) * 64 + l;
      pr = base[p]; pg = base[NPIX + p]; pb = base[2 * NPIX + p];
    }
    // wave-private LDS: in-order per wave; waitcnt orders write->read
    asm volatile("s_waitcnt lgkmcnt(0)" ::: "memory");

    // ---- two K-subtiles of 32 pixels each ----
#pragma unroll
    for (int s = 0; s < 2; ++s) {
      const int k0 = s * 32 + grp * 8;   // this lane's 8 pixels
      const f32x2* __restrict__ u2  = (const f32x2*)&stage[w][0][k0];
      const f32x2* __restrict__ v2  = (const f32x2*)&stage[w][1][k0];
      const f32x2* __restrict__ iy2 = (const f32x2*)&stage[w][2][k0];

      bf16x8 af[4];
#pragma unroll
      for (int ut = 0; ut < 4; ++ut) {
        const float dlt = d50_0 + (float)ut * dstep50;
        const f32x2 dlt2 = {dlt, dlt};
#pragma unroll
        for (int jp = 0; jp < 4; ++jp) {
          f32x2 x = u2[jp] - dlt2;
          f32x2 q = x * x + one2;                 // v_pk_fma candidates
          f32x2 rc = {__builtin_amdgcn_rcpf(q[0]), __builtin_amdgcn_rcpf(q[1])};
          f32x2 a2 = iy2[jp] * rc;
          af[ut][2 * jp]     = (__bf16)a2[0];
          af[ut][2 * jp + 1] = (__bf16)a2[1];
        }
      }

#pragma unroll
      for (int vt = 0; vt < 4; ++vt) {
        const float dlt = d50_0 + (float)vt * dstep50;
        const f32x2 dlt2 = {dlt, dlt};
        bf16x8 bf;
#pragma unroll
        for (int jp = 0; jp < 4; ++jp) {
          f32x2 x = v2[jp] - dlt2;
          f32x2 q = x * x + one2;
          bf[2 * jp]     = (__bf16)__builtin_amdgcn_rcpf(q[0]);
          bf[2 * jp + 1] = (__bf16)__builtin_amdgcn_rcpf(q[1]);
        }
#pragma unroll
        for (int ut = 0; ut < 4; ++ut)
          acc[ut * 4 + vt] =
              __builtin_amdgcn_mfma_f32_16x16x32_bf16(af[ut], bf, acc[ut * 4 + vt], 0, 0, 0);
      }
    }
  }

  // ---- vectorized tree reduction: (0+2),(1+3) -> (0+1) ----
  if (w >= 2) {
#pragma unroll
    for (int i = 0; i < 16; ++i) slab[w - 2][i][l] = acc[i];
  }
  __syncthreads();
  if (w < 2) {
#pragma unroll
    for (int i = 0; i < 16; ++i) acc[i] += slab[w][i][l];
  }
  __syncthreads();
  if (w == 1) {
#pragma unroll
    for (int i = 0; i < 16; ++i) slab[0][i][l] = acc[i];
  }
  __syncthreads();
  if (w == 0) {
    // store block partial in fragment layout: flat f32x4 index = i*64 + l
    f32x4* __restrict__ Pv = (f32x4*)(P + (size_t)blk * 4096);
#pragma unroll
    for (int i = 0; i < 16; ++i) Pv[i * 64 + l] = acc[i] + slab[0][i][l];
  }
}

// ---- stage 2: parallel partial reduction (elementwise; layout-agnostic) ----
// grid 384 x 256: thread e = (bc, s). Sums SEGB partials in-place into the
// segment-0 slice of P and atomically accumulates per-b norm.
__global__ __launch_bounds__(256) void reduce_partials(float* __restrict__ P,
                                                       float* __restrict__ norms) {
  const int e  = blockIdx.x * 256 + threadIdx.x;   // 0..98303
  const int bc = e >> 12;
  const int si = e & 4095;
  float* __restrict__ p0 = P + (size_t)(bc * SEGB) * 4096 + si;
  float s = 0.f;
#pragma unroll
  for (int sg = 0; sg < SEGB; ++sg) s += p0[(size_t)sg * 4096];
  p0[0] = s;

  __shared__ float red[4];
  float ns = s;
#pragma unroll
  for (int off = 32; off > 0; off >>= 1) ns += __shfl_down(ns, off);
  if ((threadIdx.x & 63) == 0) red[threadIdx.x >> 6] = ns;
  __syncthreads();
  if (threadIdx.x == 0)
    atomicAdd(&norms[bc / 3], red[0] + red[1] + red[2] + red[3]);
}

// ---- stage 3: Hellinger loss + fused final (last block writes out) ----
__global__ __launch_bounds__(256) void loss_final(const float* __restrict__ P,
                                                  const float* __restrict__ norms,
                                                  const float* __restrict__ th,
                                                  float* __restrict__ acc,
                                                  unsigned* __restrict__ counter,
                                                  float* __restrict__ out) {
  float s = 0.f;
  for (int idx = blockIdx.x * 256 + threadIdx.x; idx < 8 * 12288;
       idx += gridDim.x * 256) {
    const int b  = idx / 12288;
    const int r  = idx - b * 12288;
    const int c  = r >> 12;
    const int si = r & 4095;                 // fragment-permuted storage index
    // inverse permutation: si = ((i*64 + l)<<2)|rg  ->  (row,col)
    const int rg = si & 3;
    const int q  = si >> 2;
    const int l  = q & 63;
    const int i  = q >> 6;
    const int row = (i >> 2) * 16 + (l >> 4) * 4 + rg;
    const int col = (i & 3) * 16 + (l & 15);
    const float h = P[(size_t)((b * 3 + c) * SEGB) * 4096 + si] / (norms[b] + HEPS);
    const float d = sqrtf(th[c * 4096 + row * 64 + col]) - sqrtf(h);
    s += d * d;
  }
  __shared__ float red[4];
#pragma unroll
  for (int off = 32; off > 0; off >>= 1) s += __shfl_down(s, off);
  if ((threadIdx.x & 63) == 0) red[threadIdx.x >> 6] = s;
  __syncthreads();
  if (threadIdx.x == 0) {
    atomicAdd(acc, red[0] + red[1] + red[2] + red[3]);
    __threadfence();
    const unsigned old = atomicAdd(counter, 1u);
    if (old == (unsigned)(gridDim.x - 1)) {
      const float tot = atomicAdd(acc, 0.f);   // all adds visible
      out[0] = sqrtf(tot) * 0.08838834764831845f;   // (1/sqrt(2))/B, B=8
    }
  }
}

extern "C" void kernel_launch(void* const* d_in, const int* in_sizes, int n_in,
                              void* d_out, int out_size, void* d_ws, size_t ws_size,
                              hipStream_t stream) {
  const float* rgbd = (const float*)d_in[0];   // [8,4,256,256]
  const float* th   = (const float*)d_in[1];   // [3,64,64]
  float* out = (float*)d_out;

  const size_t nP = (size_t)24 * SEGB * 4096;   // partial hists (12.6 MB)
  float*    P       = (float*)d_ws;
  float*    ctrl    = P + nP;                   // norms[8], acc, counter, pad
  float*    norms   = ctrl;
  float*    acc     = ctrl + 8;
  unsigned* counter = (unsigned*)(ctrl + 9);

  hist_mfma<<<24 * SEGB, 256, 0, stream>>>(rgbd, P, ctrl);
  reduce_partials<<<384, 256, 0, stream>>>(P, norms);
  loss_final<<<96, 256, 0, stream>>>(P, norms, th, acc, counter, out);
}